// Round 4
// baseline (1182.675 us; speedup 1.0000x reference)
//
#include <hip/hip_runtime.h>

typedef _Float16 half2_t __attribute__((ext_vector_type(2)));

#define NB 512
#define NS 512
#define NI 64
#define NH 100
#define NO 7
#define WROW 168    // x(64) + ctx(4) + h(100)
#define KPH 112     // h padded to 4*28
#define QH 28       // per-quarter h slice (halves)

__device__ __forceinline__ float dot2f(half2_t a, half2_t b, float c) {
    return __builtin_amdgcn_fdot2(a, b, c, false);
}
__device__ __forceinline__ half2_t pack2(float a, float b) {
    half2_t r; r[0] = (_Float16)a; r[1] = (_Float16)b; return r;
}

// ============================================================================
// Kernel 1: x-projection GEMM. xf = x@Wf_x^T + (Wf_b + Wf_ctx@ctx), xh likewise.
// Packed f16 into the hid region of d_out: row r (=b*512+t) holds
// [xf[0..99] | xh[0..99]] as 200 f16 = 400B = exactly the future hid row.
// Block: 256 threads, 256 rows. thread=(rg 0..63, c 0..3): 4 rows x 25 outs.
// ============================================================================
__global__ __launch_bounds__(256, 2) void proj_gemm(
    const float* __restrict__ x, const float* __restrict__ ctx,
    const float* __restrict__ Wf_w, const float* __restrict__ Wf_b,
    const float* __restrict__ Wh_w, const float* __restrict__ Wh_b,
    float* __restrict__ out)
{
    __shared__ half2_t wlds[2][NH][36];   // 36-stride: 16B-aligned rows, bank-spread
    __shared__ float   blds[2][NH];
    const int tid = threadIdx.x;

    for (int idx = tid; idx < 2 * NH * 32; idx += 256) {
        const int m = idx / (NH * 32), rem = idx % (NH * 32);
        const int j = rem >> 5, kk = rem & 31;
        const float* W = m ? Wh_w : Wf_w;
        wlds[m][j][kk] = pack2(W[j * WROW + 2 * kk], W[j * WROW + 2 * kk + 1]);
    }
    const float c0 = ctx[0], c1 = ctx[1], c2 = ctx[2], c3 = ctx[3];
    for (int idx = tid; idx < 2 * NH; idx += 256) {
        const int m = idx / NH, j = idx % NH;
        const float* W = m ? Wh_w : Wf_w;
        const float* Bv = m ? Wh_b : Wf_b;
        blds[m][j] = Bv[j] + W[j*WROW+64]*c0 + W[j*WROW+65]*c1 + W[j*WROW+66]*c2 + W[j*WROW+67]*c3;
    }
    __syncthreads();

    const int rg = tid >> 2, c = tid & 3;
    const size_t row0 = (size_t)blockIdx.x * 256 + 4 * rg;

    // 4 rows of x -> f16 regs (sequential 16B reads per lane: L1-friendly)
    half2_t xv[4][32];
    const float* xrow = x + row0 * NI;
    #pragma unroll
    for (int ri = 0; ri < 4; ++ri)
        #pragma unroll
        for (int kk = 0; kk < 16; ++kk) {
            const float4 v = *(const float4*)(xrow + ri * NI + kk * 4);
            xv[ri][2*kk]   = pack2(v.x, v.y);
            xv[ri][2*kk+1] = pack2(v.z, v.w);
        }

    _Float16* opack = (_Float16*)(out + NB * NO);
    for (int m = 0; m < 2; ++m)
        for (int o = 0; o < 25; ++o) {
            const int j = c * 25 + o;
            half2_t wrow[32];
            #pragma unroll
            for (int kk = 0; kk < 32; ++kk) wrow[kk] = wlds[m][j][kk];
            float a0 = blds[m][j], a1 = a0, a2 = a0, a3 = a0;
            #pragma unroll
            for (int kk = 0; kk < 32; ++kk) {
                a0 = dot2f(wrow[kk], xv[0][kk], a0);
                a1 = dot2f(wrow[kk], xv[1][kk], a1);
                a2 = dot2f(wrow[kk], xv[2][kk], a2);
                a3 = dot2f(wrow[kk], xv[3][kk], a3);
            }
            _Float16* op = opack + row0 * 200 + m * NH + j;
            op[0]   = (_Float16)a0;
            op[200] = (_Float16)a1;
            op[400] = (_Float16)a2;
            op[600] = (_Float16)a3;
        }
}

// ============================================================================
// Kernel 2: recurrence scan. ONE WAVE per batch row; no __syncthreads.
// lane = g*4+q: g=output group (7 outs: j=7g..7g+6), q=K-quarter of h (28 halves).
// Recurrent weights in VGPRs (196 half2). h/g via 448B LDS, wave-sync ordering.
// Lane q finalizes outputs oA=q and (q<3) oB=4+q of its group.
// ============================================================================
__global__ __launch_bounds__(64, 1) void agent_scan(
    const float* __restrict__ Wf_w, const float* __restrict__ Wh_w,
    const float* __restrict__ ro_w, const float* __restrict__ ro_b,
    float* __restrict__ out)
{
    const int b    = blockIdx.x;
    const int lane = threadIdx.x;
    const int g    = lane >> 2, q = lane & 3;

    __shared__ __align__(16) _Float16 vh[KPH];
    __shared__ __align__(16) _Float16 vg[KPH];
    __shared__ float hfin[NH];

    for (int i = lane; i < KPH; i += 64) { vh[i] = (_Float16)0.f; vg[i] = (_Float16)0.f; }

    // ---- recurrent weights -> VGPRs: 7 outs x 14 half2 x 2 mats
    half2_t wf[7][14], wh[7][14];
    #pragma unroll
    for (int o = 0; o < 7; ++o) {
        const int j = 7 * g + o;
        const bool v = (j < NH);
        const int jc = v ? j : NH - 1;
        const float* rf = Wf_w + (size_t)jc * WROW + 68;
        const float* rh = Wh_w + (size_t)jc * WROW + 68;
        #pragma unroll
        for (int u = 0; u < 14; ++u) {
            const int k0 = QH * q + 2 * u, k1 = k0 + 1;
            const float f0 = (v && k0 < NH) ? rf[k0] : 0.f;
            const float f1 = (v && k1 < NH) ? rf[k1] : 0.f;
            const float g0 = (v && k0 < NH) ? rh[k0] : 0.f;
            const float g1 = (v && k1 < NH) ? rh[k1] : 0.f;
            wf[o][u] = pack2(f0, f1);
            wh[o][u] = pack2(g0, g1);
        }
    }

    const int jA = 7 * g + q;
    const int jB = 7 * g + 4 + q;
    const bool hasA = (jA < NH);
    const bool hasB = (q < 3) && (jB < NH);
    const int jAc = hasA ? jA : 0;
    const int jBc = hasB ? jB : 0;
    const int oB  = (q < 3) ? 4 + q : 0;

    const unsigned short* pux = (const unsigned short*)(out + NB * NO) + (size_t)b * NS * 200;
    float* hidbase = out + NB * NO + (size_t)b * NS * NH;

    float hA = 0.f, hB = 0.f;
    // preload xf/xh for t=0
    unsigned short uA0 = pux[jAc], uB0 = pux[jBc];
    unsigned short uA1 = pux[NH + jAc], uB1 = pux[NH + jBc];

    __asm__ volatile("s_waitcnt lgkmcnt(0)" ::: "memory");  // LDS zeros visible

    for (int t = 0; t < NS; ++t) {
        // prefetch next step's xf/xh (clamped at the tail; values unused then)
        const unsigned short* nr = pux + (size_t)((t + 1 < NS) ? t + 1 : t) * 200;
        const unsigned short nA0 = nr[jAc], nB0 = nr[jBc];
        const unsigned short nA1 = nr[NH + jAc], nB1 = nr[NH + jBc];

        // ---- phase A: zf[j] = xf[j] + Wf_h[j,:].h
        float acc[7] = {0.f, 0.f, 0.f, 0.f, 0.f, 0.f, 0.f};
        {
            const half2_t* ph = (const half2_t*)(vh + QH * q);
            half2_t p[14];
            #pragma unroll
            for (int u = 0; u < 14; ++u) p[u] = ph[u];
            #pragma unroll
            for (int o = 0; o < 7; ++o)
                #pragma unroll
                for (int u = 0; u < 14; ++u) acc[o] = dot2f(wf[o][u], p[u], acc[o]);
        }
        #pragma unroll
        for (int o = 0; o < 7; ++o) {
            float s = acc[o];
            s += __shfl_xor(s, 1); s += __shfl_xor(s, 2);
            acc[o] = s;
        }
        const float xfA = (float)__builtin_bit_cast(_Float16, uA0);
        const float xfB = (float)__builtin_bit_cast(_Float16, uB0);
        const float fA = __fdividef(1.f, 1.f + __expf(-(xfA + acc[q])));
        const float fB = __fdividef(1.f, 1.f + __expf(-(xfB + acc[oB])));
        if (hasA) vg[jA] = (_Float16)(fA * hA);
        if (hasB) vg[jB] = (_Float16)(fB * hB);
        __asm__ volatile("s_waitcnt lgkmcnt(0)" ::: "memory");  // g visible (in-order DS)

        // ---- phase C: zh[j] = xh[j] + Wh_h[j,:].(f*h)
        #pragma unroll
        for (int o = 0; o < 7; ++o) acc[o] = 0.f;
        {
            const half2_t* pg = (const half2_t*)(vg + QH * q);
            half2_t p[14];
            #pragma unroll
            for (int u = 0; u < 14; ++u) p[u] = pg[u];
            #pragma unroll
            for (int o = 0; o < 7; ++o)
                #pragma unroll
                for (int u = 0; u < 14; ++u) acc[o] = dot2f(wh[o][u], p[u], acc[o]);
        }
        #pragma unroll
        for (int o = 0; o < 7; ++o) {
            float s = acc[o];
            s += __shfl_xor(s, 1); s += __shfl_xor(s, 2);
            acc[o] = s;
        }
        const float xhA = (float)__builtin_bit_cast(_Float16, uA1);
        const float xhB = (float)__builtin_bit_cast(_Float16, uB1);
        // tanh(z) = 1 - 2/(e^{2z}+1)
        const float eA = __expf(2.f * (xhA + acc[q]));
        const float eB = __expf(2.f * (xhB + acc[oB]));
        const float thA = 1.f - __fdividef(2.f, eA + 1.f);
        const float thB = 1.f - __fdividef(2.f, eB + 1.f);
        hA = hA + fA * (thA - hA);
        hB = hB + fB * (thB - hB);

        float* hrow = hidbase + (size_t)t * NH;
        if (hasA) { vh[jA] = (_Float16)hA; hrow[jA] = hA; }
        if (hasB) { vh[jB] = (_Float16)hB; hrow[jB] = hB; }
        uA0 = nA0; uB0 = nB0; uA1 = nA1; uB1 = nB1;
        __asm__ volatile("s_waitcnt lgkmcnt(0)" ::: "memory");  // h_{t+1} visible
    }

    // ---- readout
    if (hasA) hfin[jA] = hA;
    if (hasB) hfin[jB] = hB;
    __asm__ volatile("s_waitcnt lgkmcnt(0)" ::: "memory");
    if (lane < NO) {
        float acc = ro_b[lane];
        const float* rr = ro_w + lane * NH;
        #pragma unroll 4
        for (int i = 0; i < NH; ++i) acc += rr[i] * hfin[i];
        out[b * NO + lane] = acc;
    }
}

extern "C" void kernel_launch(void* const* d_in, const int* in_sizes, int n_in,
                              void* d_out, int out_size, void* d_ws, size_t ws_size,
                              hipStream_t stream) {
    const float* x    = (const float*)d_in[0];
    const float* ctx  = (const float*)d_in[1];
    const float* Wf_w = (const float*)d_in[2];
    const float* Wf_b = (const float*)d_in[3];
    const float* Wh_w = (const float*)d_in[4];
    const float* Wh_b = (const float*)d_in[5];
    const float* ro_w = (const float*)d_in[6];
    const float* ro_b = (const float*)d_in[7];
    (void)in_sizes; (void)n_in; (void)out_size; (void)d_ws; (void)ws_size;
    float* out = (float*)d_out;

    proj_gemm<<<dim3((NB * NS) / 256), dim3(256), 0, stream>>>(x, ctx, Wf_w, Wf_b, Wh_w, Wh_b, out);
    agent_scan<<<dim3(NB), dim3(64), 0, stream>>>(Wf_w, Wh_w, ro_w, ro_b, out);
}

// Round 6
// 880.315 us; speedup vs baseline: 1.3435x; 1.3435x over previous
//
#include <hip/hip_runtime.h>

typedef _Float16 half2_t __attribute__((ext_vector_type(2)));

#define NB 512
#define NS 512
#define NI 64
#define NH 100
#define NO 7
#define WROW 168    // x(64) + ctx(4) + h(100)

__device__ __forceinline__ float dot2f(half2_t a, half2_t b, float c) {
    return __builtin_amdgcn_fdot2(a, b, c, false);
}
__device__ __forceinline__ half2_t pack2(float a, float b) {
    half2_t r; r[0] = (_Float16)a; r[1] = (_Float16)b; return r;
}
__device__ __forceinline__ unsigned pack2u(float a, float b) {
    return __builtin_bit_cast(unsigned, pack2(a, b));
}
__device__ __forceinline__ half2_t h2(unsigned u) {
    return __builtin_bit_cast(half2_t, u);
}

// ============================================================================
// ONE kernel, one wave per batch row, fused x-projection + scan.
// Lane owns outputs j0=2*lane, j0+1 with FULL K: no shuffles, no reductions,
// no __syncthreads, no s_waitcnt for LDS ordering (DS is in-order per wave).
// h/g/x broadcast through LDS (same-address b128 reads). Weights in VGPRs
// as packed f16 (328 half2). x prefetched 2 steps ahead.
// ============================================================================
__global__ __launch_bounds__(64, 1) void agent_scan(
    const float* __restrict__ x,     // [B,S,64]
    const float* __restrict__ ctx,   // [4]
    const float* __restrict__ Wf_w,  // [100,168]
    const float* __restrict__ Wf_b,  // [100]
    const float* __restrict__ Wh_w,  // [100,168]
    const float* __restrict__ Wh_b,  // [100]
    const float* __restrict__ ro_w,  // [7,100]
    const float* __restrict__ ro_b,  // [7]
    float* __restrict__ out)         // [512*7] ++ [512,512,100]
{
    const int b = blockIdx.x, lane = threadIdx.x;
    const int j0 = 2 * lane;
    const bool act = (lane < NH / 2);

    __shared__ __align__(16) unsigned vx[32];   // x_t as 64 f16
    __shared__ __align__(16) unsigned vh[52];   // h as 104 f16 (100 + zero pad)
    __shared__ __align__(16) unsigned vg[52];   // f*h
    __shared__ __align__(16) float hfin[NH];

    if (lane < 52) { vh[lane] = 0u; vg[lane] = 0u; }

    // ---- weights -> f16 register pairs (zeroed for inactive lanes)
    const float s = act ? 1.f : 0.f;
    const int jc0 = act ? j0 : 0;
    half2_t wfx[2][32], whx[2][32], wfh[2][50], whh[2][50];
    float cf[2], ch[2];
    const float c0 = ctx[0], c1 = ctx[1], c2 = ctx[2], c3 = ctx[3];
    #pragma unroll
    for (int o = 0; o < 2; ++o) {
        const float* rf = Wf_w + (size_t)(jc0 + o) * WROW;
        const float* rh = Wh_w + (size_t)(jc0 + o) * WROW;
        #pragma unroll
        for (int u = 0; u < 16; ++u) {                       // x-cols 0..63
            const float4 a  = *(const float4*)(rf + 4 * u);
            const float4 bb = *(const float4*)(rh + 4 * u);
            wfx[o][2*u]   = pack2(s * a.x,  s * a.y);
            wfx[o][2*u+1] = pack2(s * a.z,  s * a.w);
            whx[o][2*u]   = pack2(s * bb.x, s * bb.y);
            whx[o][2*u+1] = pack2(s * bb.z, s * bb.w);
        }
        #pragma unroll
        for (int u = 0; u < 25; ++u) {                       // h-cols 68..167
            const float4 a  = *(const float4*)(rf + 68 + 4 * u);
            const float4 bb = *(const float4*)(rh + 68 + 4 * u);
            wfh[o][2*u]   = pack2(s * a.x,  s * a.y);
            wfh[o][2*u+1] = pack2(s * a.z,  s * a.w);
            whh[o][2*u]   = pack2(s * bb.x, s * bb.y);
            whh[o][2*u+1] = pack2(s * bb.z, s * bb.w);
        }
        const float4 cfv = *(const float4*)(rf + 64);        // ctx cols 64..67
        const float4 chv = *(const float4*)(rh + 64);
        cf[o] = Wf_b[jc0+o] + cfv.x*c0 + cfv.y*c1 + cfv.z*c2 + cfv.w*c3;
        ch[o] = Wh_b[jc0+o] + chv.x*c0 + chv.y*c1 + chv.z*c2 + chv.w*c3;
    }

    // ---- stage x_0; prefetch x_1
    const float* xrow = x + (size_t)b * NS * NI;
    float4 xp = make_float4(0.f, 0.f, 0.f, 0.f);
    if (lane < 16) {
        const float4 v = *(const float4*)(xrow + 4 * lane);
        *(uint2*)&vx[2*lane] = make_uint2(pack2u(v.x, v.y), pack2u(v.z, v.w));
        xp = *(const float4*)(xrow + NI + 4 * lane);
    }
    asm volatile("" ::: "memory");

    float* hidbase = out + NB * NO + (size_t)b * NS * NH;
    float h0 = 0.f, h1 = 0.f;

    for (int t = 0; t < NS; ++t) {
        // broadcast-read x_t and h_t from LDS
        half2_t xb[32];
        #pragma unroll
        for (int r = 0; r < 8; ++r) {
            const uint4 v = *(const uint4*)&vx[4*r];
            xb[4*r] = h2(v.x); xb[4*r+1] = h2(v.y); xb[4*r+2] = h2(v.z); xb[4*r+3] = h2(v.w);
        }
        half2_t hb[52];
        #pragma unroll
        for (int r = 0; r < 13; ++r) {
            const uint4 v = *(const uint4*)&vh[4*r];
            hb[4*r] = h2(v.x); hb[4*r+1] = h2(v.y); hb[4*r+2] = h2(v.z); hb[4*r+3] = h2(v.w);
        }
        asm volatile("" ::: "memory");
        // stage x_{t+1} (WAR after xb reads; DS in-order per wave), prefetch x_{t+2}
        if (lane < 16)
            *(uint2*)&vx[2*lane] = make_uint2(pack2u(xp.x, xp.y), pack2u(xp.z, xp.w));
        {
            const int tn = (t + 2 < NS) ? t + 2 : NS - 1;
            if (lane < 16) xp = *(const float4*)(xrow + (size_t)tn * NI + 4 * lane);
        }

        // x-dots for BOTH gates (h-independent; fills LDS latency)
        float af0=0.f, af1=0.f, ag0=0.f, ag1=0.f;   // f-gate x-part
        float ah0=0.f, ah1=0.f, ai0=0.f, ai1=0.f;   // cand  x-part
        #pragma unroll
        for (int u = 0; u < 32; u += 2) {
            af0 = dot2f(wfx[0][u],   xb[u],   af0);
            af1 = dot2f(wfx[0][u+1], xb[u+1], af1);
            ag0 = dot2f(wfx[1][u],   xb[u],   ag0);
            ag1 = dot2f(wfx[1][u+1], xb[u+1], ag1);
            ah0 = dot2f(whx[0][u],   xb[u],   ah0);
            ah1 = dot2f(whx[0][u+1], xb[u+1], ah1);
            ai0 = dot2f(whx[1][u],   xb[u],   ai0);
            ai1 = dot2f(whx[1][u+1], xb[u+1], ai1);
        }
        // h-dots, f-gate
        float bf0=0.f, bf1=0.f, bg0=0.f, bg1=0.f;
        #pragma unroll
        for (int u = 0; u < 50; u += 2) {
            bf0 = dot2f(wfh[0][u],   hb[u],   bf0);
            bf1 = dot2f(wfh[0][u+1], hb[u+1], bf1);
            bg0 = dot2f(wfh[1][u],   hb[u],   bg0);
            bg1 = dot2f(wfh[1][u+1], hb[u+1], bg1);
        }
        const float zf0 = cf[0] + af0 + af1 + bf0 + bf1;
        const float zf1 = cf[1] + ag0 + ag1 + bg0 + bg1;
        const float f0 = __fdividef(1.f, 1.f + __expf(-zf0));
        const float f1 = __fdividef(1.f, 1.f + __expf(-zf1));

        if (act) vg[lane] = pack2u(f0 * h0, f1 * h1);
        asm volatile("" ::: "memory");

        // candidate h-dots on g = f*h
        half2_t gb[52];
        #pragma unroll
        for (int r = 0; r < 13; ++r) {
            const uint4 v = *(const uint4*)&vg[4*r];
            gb[4*r] = h2(v.x); gb[4*r+1] = h2(v.y); gb[4*r+2] = h2(v.z); gb[4*r+3] = h2(v.w);
        }
        float bh0=0.f, bh1=0.f, bi0=0.f, bi1=0.f;
        #pragma unroll
        for (int u = 0; u < 50; u += 2) {
            bh0 = dot2f(whh[0][u],   gb[u],   bh0);
            bh1 = dot2f(whh[0][u+1], gb[u+1], bh1);
            bi0 = dot2f(whh[1][u],   gb[u],   bi0);
            bi1 = dot2f(whh[1][u+1], gb[u+1], bi1);
        }
        const float zh0 = ch[0] + ah0 + ah1 + bh0 + bh1;
        const float zh1 = ch[1] + ai0 + ai1 + bi0 + bi1;
        // tanh(z) = 1 - 2/(e^{2z}+1)
        const float e0 = __expf(2.f * zh0), e1 = __expf(2.f * zh1);
        const float th0 = 1.f - __fdividef(2.f, e0 + 1.f);
        const float th1 = 1.f - __fdividef(2.f, e1 + 1.f);
        h0 += f0 * (th0 - h0);
        h1 += f1 * (th1 - h1);

        if (act) {
            vh[lane] = pack2u(h0, h1);
            *(float2*)(hidbase + (size_t)t * NH + j0) = make_float2(h0, h1);
        }
        asm volatile("" ::: "memory");
    }

    // ---- readout
    if (act) *(float2*)&hfin[j0] = make_float2(h0, h1);
    asm volatile("" ::: "memory");
    if (lane < NO) {
        float acc = ro_b[lane];
        const float* rr = ro_w + lane * NH;
        #pragma unroll
        for (int u = 0; u < 25; ++u) {
            const float4 v = *(const float4*)(rr + 4 * u);
            acc += v.x * hfin[4*u] + v.y * hfin[4*u+1] + v.z * hfin[4*u+2] + v.w * hfin[4*u+3];
        }
        out[b * NO + lane] = acc;
    }
}

extern "C" void kernel_launch(void* const* d_in, const int* in_sizes, int n_in,
                              void* d_out, int out_size, void* d_ws, size_t ws_size,
                              hipStream_t stream) {
    const float* x    = (const float*)d_in[0];
    const float* ctx  = (const float*)d_in[1];
    const float* Wf_w = (const float*)d_in[2];
    const float* Wf_b = (const float*)d_in[3];
    const float* Wh_w = (const float*)d_in[4];
    const float* Wh_b = (const float*)d_in[5];
    const float* ro_w = (const float*)d_in[6];
    const float* ro_b = (const float*)d_in[7];
    (void)in_sizes; (void)n_in; (void)out_size; (void)d_ws; (void)ws_size;
    agent_scan<<<dim3(NB), dim3(64), 0, stream>>>(x, ctx, Wf_w, Wf_b, Wh_w, Wh_b, ro_w, ro_b, (float*)d_out);
}

// Round 7
// 767.471 us; speedup vs baseline: 1.5410x; 1.1470x over previous
//
#include <hip/hip_runtime.h>

typedef _Float16 half2_t __attribute__((ext_vector_type(2)));

#define NB 512
#define NS 512
#define NI 64
#define NH 100
#define NO 7
#define WROW 168    // x(64) + ctx(4) + h(100)

__device__ __forceinline__ float dot2f(half2_t a, half2_t b, float c) {
    return __builtin_amdgcn_fdot2(a, b, c, false);
}
__device__ __forceinline__ half2_t pack2(float a, float b) {
    half2_t r; r[0] = (_Float16)a; r[1] = (_Float16)b; return r;
}
__device__ __forceinline__ half2_t h2u(unsigned u) { return __builtin_bit_cast(half2_t, u); }
__device__ __forceinline__ float f16lo(unsigned u) {
    return (float)__builtin_bit_cast(_Float16, (unsigned short)(u & 0xffffu));
}
__device__ __forceinline__ float f16hi(unsigned u) {
    return (float)__builtin_bit_cast(_Float16, (unsigned short)(u >> 16));
}
// sum over each aligned 4-lane quad via DPP quad-perm (VALU-speed, no DS pipe)
__device__ __forceinline__ float qsum4(float v) {
    int i = __builtin_bit_cast(int, v);
    int t = __builtin_amdgcn_update_dpp(0, i, 0xB1, 0xF, 0xF, true);  // [1,0,3,2]
    v += __builtin_bit_cast(float, t);
    i = __builtin_bit_cast(int, v);
    t = __builtin_amdgcn_update_dpp(0, i, 0x4E, 0xF, 0xF, true);      // [2,3,0,1]
    v += __builtin_bit_cast(float, t);
    return v;
}

// ============================================================================
// K1: xf/xh projection. Row r=(b*512+t) gets [xf[0..99] | xh[0..99]] as 200
// f16 = 400 B, overlaid on the future hid row (scan reads row t+4 before
// writing hid row t). Thread-per-row; W (200x64) broadcast from LDS.
// ============================================================================
__global__ __launch_bounds__(256, 4) void proj_gemm(
    const float* __restrict__ x, const float* __restrict__ ctx,
    const float* __restrict__ Wf_w, const float* __restrict__ Wf_b,
    const float* __restrict__ Wh_w, const float* __restrict__ Wh_b,
    float* __restrict__ out)
{
    __shared__ __align__(16) half2_t wl[200][32];   // 25.6 KB
    __shared__ float bl[200];
    const int tid = threadIdx.x;

    for (int idx = tid; idx < 200 * 32; idx += 256) {
        const int j = idx >> 5, u = idx & 31;
        const float* W = (j < 100) ? (Wf_w + (size_t)j * WROW)
                                   : (Wh_w + (size_t)(j - 100) * WROW);
        wl[j][u] = pack2(W[2 * u], W[2 * u + 1]);
    }
    const float c0 = ctx[0], c1 = ctx[1], c2 = ctx[2], c3 = ctx[3];
    for (int j = tid; j < 200; j += 256) {
        const float* W; float bb;
        if (j < 100) { W = Wf_w + (size_t)j * WROW;        bb = Wf_b[j]; }
        else         { W = Wh_w + (size_t)(j - 100) * WROW; bb = Wh_b[j - 100]; }
        bl[j] = bb + W[64]*c0 + W[65]*c1 + W[66]*c2 + W[67]*c3;
    }
    __syncthreads();

    const size_t row = (size_t)blockIdx.x * 256 + tid;
    const float* xp = x + row * NI;
    half2_t xr[32];
    #pragma unroll
    for (int u = 0; u < 16; ++u) {
        const float4 v = *(const float4*)(xp + 4 * u);
        xr[2*u]   = pack2(v.x, v.y);
        xr[2*u+1] = pack2(v.z, v.w);
    }
    unsigned* orow = (unsigned*)((_Float16*)(out + NB * NO) + row * 200);
    #pragma unroll 1
    for (int c = 0; c < 25; ++c) {
        float acc[8];
        #pragma unroll
        for (int jj = 0; jj < 8; ++jj) {
            const int j = 8 * c + jj;
            float a0 = bl[j], a1 = 0.f;
            const uint4* wr = (const uint4*)&wl[j][0];
            #pragma unroll
            for (int u = 0; u < 8; ++u) {
                const uint4 wv = wr[u];
                a0 = dot2f(h2u(wv.x), xr[4*u],   a0);
                a1 = dot2f(h2u(wv.y), xr[4*u+1], a1);
                a0 = dot2f(h2u(wv.z), xr[4*u+2], a0);
                a1 = dot2f(h2u(wv.w), xr[4*u+3], a1);
            }
            acc[jj] = a0 + a1;
        }
        uint4 st;
        st.x = __builtin_bit_cast(unsigned, pack2(acc[0], acc[1]));
        st.y = __builtin_bit_cast(unsigned, pack2(acc[2], acc[3]));
        st.z = __builtin_bit_cast(unsigned, pack2(acc[4], acc[5]));
        st.w = __builtin_bit_cast(unsigned, pack2(acc[6], acc[7]));
        *(uint4*)&orow[4 * c] = st;
    }
}

// ============================================================================
// K2: recurrence scan. One wave per batch row. lane=(g=lane>>2, q=lane&3).
// Group g owns outputs j = g + 16*o (o<7, j<100). Lane holds K-quarter
// q (h-halves [26q,26q+26)) of its group's rows: 182 half2 in VGPRs.
// vh/vg LDS layout: h[k] at half-index 32*(k/26) + k%26 (quarters 16B-aligned,
// pads zero). 4-lane DPP reduction; finalizers: lane q owns o=q and o=q+4.
// xf/xh consumed from the f16 overlay via a 4-deep static prefetch ring.
// No barriers; single-wave in-order DS + compiler fences.
// ============================================================================
__global__ __launch_bounds__(64, 1) void agent_scan(
    const float* __restrict__ Wf_w, const float* __restrict__ Wh_w,
    const float* __restrict__ ro_w, const float* __restrict__ ro_b,
    float* __restrict__ out)
{
    const int b = blockIdx.x, lane = threadIdx.x;
    const int g = lane >> 2, q = lane & 3;

    __shared__ __align__(16) _Float16 vh[128];
    __shared__ __align__(16) _Float16 vg[128];
    __shared__ float hfin[NH];

    ((unsigned*)vh)[lane] = 0u;   // 128 halves zeroed
    ((unsigned*)vg)[lane] = 0u;

    // ---- recurrent weights -> VGPRs: 7 outs x 13 half2 x 2 mats = 182
    half2_t wf[7][13], wh[7][13];
    #pragma unroll
    for (int o = 0; o < 7; ++o) {
        const int j = g + 16 * o;
        const bool valid = (j < NH);
        const float* rf = Wf_w + (size_t)(valid ? j : 0) * WROW + 68;
        const float* rh = Wh_w + (size_t)(valid ? j : 0) * WROW + 68;
        #pragma unroll
        for (int u = 0; u < 13; ++u) {
            const int k0 = 26 * q + 2 * u, k1 = k0 + 1;
            const float f0 = (valid && k0 < NH) ? rf[k0] : 0.f;
            const float f1 = (valid && k1 < NH) ? rf[k1] : 0.f;
            const float g0 = (valid && k0 < NH) ? rh[k0] : 0.f;
            const float g1 = (valid && k1 < NH) ? rh[k1] : 0.f;
            wf[o][u] = pack2(f0, f1);
            wh[o][u] = pack2(g0, g1);
        }
    }

    // finalizer slots: A = (o=q) always valid (j<=63); B = (o=q+4)
    const int jA = g + 16 * q;
    const int jB = g + 16 * (q + 4);
    const bool hasB = (q <= 2) && (jB < NH);
    const int jBc = hasB ? jB : 0;
    const int posA = 32 * (jA / 26) + jA % 26;
    const int posB = 32 * (jBc / 26) + jBc % 26;

    const unsigned short* xq = (const unsigned short*)(out + NB * NO) + (size_t)b * NS * 200;
    float* hid = out + NB * NO + (size_t)b * NS * NH;

    // ---- 4-deep prefetch ring (packed xf | xh<<16), static indices only
    unsigned ringA[4], ringB[4];
    #pragma unroll
    for (int d = 0; d < 4; ++d) {
        const size_t ro = (size_t)d * 200;
        ringA[d] = (unsigned)xq[ro + jA]  | ((unsigned)xq[ro + 100 + jA]  << 16);
        ringB[d] = (unsigned)xq[ro + jBc] | ((unsigned)xq[ro + 100 + jBc] << 16);
    }

    float hA = 0.f, hB = 0.f;
    asm volatile("" ::: "memory");

    auto step = [&](int t, int dd) {
        // ---- phase A: read h quarter, dot, reduce
        const uint4 v0 = *(const uint4*)(vh + 32 * q);
        const uint4 v1 = *(const uint4*)(vh + 32 * q + 8);
        const uint4 v2 = *(const uint4*)(vh + 32 * q + 16);
        const unsigned v3 = *(const unsigned*)(vh + 32 * q + 24);
        half2_t p[13];
        p[0]=h2u(v0.x); p[1]=h2u(v0.y); p[2]=h2u(v0.z); p[3]=h2u(v0.w);
        p[4]=h2u(v1.x); p[5]=h2u(v1.y); p[6]=h2u(v1.z); p[7]=h2u(v1.w);
        p[8]=h2u(v2.x); p[9]=h2u(v2.y); p[10]=h2u(v2.z); p[11]=h2u(v2.w);
        p[12]=h2u(v3);

        float af[7];
        #pragma unroll
        for (int o = 0; o < 7; ++o) {
            float a = 0.f;
            #pragma unroll
            for (int u = 0; u < 13; ++u) a = dot2f(wf[o][u], p[u], a);
            af[o] = qsum4(a);
        }
        const float zA = (q == 0) ? af[0] : (q == 1) ? af[1] : (q == 2) ? af[2] : af[3];
        const float zB = (q == 0) ? af[4] : (q == 1) ? af[5] : af[6];
        const float fA = __fdividef(1.f, 1.f + __expf(-(zA + f16lo(ringA[dd]))));
        const float fB = __fdividef(1.f, 1.f + __expf(-(zB + f16lo(ringB[dd]))));

        vg[posA] = (_Float16)(fA * hA);
        if (hasB) vg[posB] = (_Float16)(fB * hB);
        asm volatile("" ::: "memory");

        // ---- phase C: read g quarter, dot, reduce
        const uint4 w0 = *(const uint4*)(vg + 32 * q);
        const uint4 w1 = *(const uint4*)(vg + 32 * q + 8);
        const uint4 w2 = *(const uint4*)(vg + 32 * q + 16);
        const unsigned w3 = *(const unsigned*)(vg + 32 * q + 24);
        half2_t r[13];
        r[0]=h2u(w0.x); r[1]=h2u(w0.y); r[2]=h2u(w0.z); r[3]=h2u(w0.w);
        r[4]=h2u(w1.x); r[5]=h2u(w1.y); r[6]=h2u(w1.z); r[7]=h2u(w1.w);
        r[8]=h2u(w2.x); r[9]=h2u(w2.y); r[10]=h2u(w2.z); r[11]=h2u(w2.w);
        r[12]=h2u(w3);

        float ah[7];
        #pragma unroll
        for (int o = 0; o < 7; ++o) {
            float a = 0.f;
            #pragma unroll
            for (int u = 0; u < 13; ++u) a = dot2f(wh[o][u], r[u], a);
            ah[o] = qsum4(a);
        }
        const float yA = (q == 0) ? ah[0] : (q == 1) ? ah[1] : (q == 2) ? ah[2] : ah[3];
        const float yB = (q == 0) ? ah[4] : (q == 1) ? ah[5] : ah[6];
        // tanh(z) = 1 - 2/(e^{2z}+1)
        const float eA = __expf(2.f * (yA + f16hi(ringA[dd])));
        const float eB = __expf(2.f * (yB + f16hi(ringB[dd])));
        const float thA = 1.f - __fdividef(2.f, eA + 1.f);
        const float thB = 1.f - __fdividef(2.f, eB + 1.f);
        hA += fA * (thA - hA);
        hB += fB * (thB - hB);

        vh[posA] = (_Float16)hA;
        if (hasB) vh[posB] = (_Float16)hB;
        float* hrow = hid + (size_t)t * NH;
        hrow[jA] = hA;
        if (hasB) hrow[jB] = hB;

        // ---- refill ring for t+4 (after the stores: consumers 4 steps out)
        const int rr = (t + 4 < NS) ? t + 4 : NS - 1;
        const size_t ro = (size_t)rr * 200;
        ringA[dd] = (unsigned)xq[ro + jA]  | ((unsigned)xq[ro + 100 + jA]  << 16);
        ringB[dd] = (unsigned)xq[ro + jBc] | ((unsigned)xq[ro + 100 + jBc] << 16);
        asm volatile("" ::: "memory");
    };

    for (int tt = 0; tt < NS; tt += 4) {
        step(tt, 0); step(tt + 1, 1); step(tt + 2, 2); step(tt + 3, 3);
    }

    // ---- readout
    hfin[jA] = hA;
    if (hasB) hfin[jB] = hB;
    asm volatile("" ::: "memory");
    if (lane < NO) {
        float acc = ro_b[lane];
        const float* rr = ro_w + lane * NH;
        #pragma unroll
        for (int u = 0; u < 25; ++u) {
            const float4 v = *(const float4*)(rr + 4 * u);
            acc += v.x * hfin[4*u] + v.y * hfin[4*u+1] + v.z * hfin[4*u+2] + v.w * hfin[4*u+3];
        }
        out[b * NO + lane] = acc;
    }
}

extern "C" void kernel_launch(void* const* d_in, const int* in_sizes, int n_in,
                              void* d_out, int out_size, void* d_ws, size_t ws_size,
                              hipStream_t stream) {
    const float* x    = (const float*)d_in[0];
    const float* ctx  = (const float*)d_in[1];
    const float* Wf_w = (const float*)d_in[2];
    const float* Wf_b = (const float*)d_in[3];
    const float* Wh_w = (const float*)d_in[4];
    const float* Wh_b = (const float*)d_in[5];
    const float* ro_w = (const float*)d_in[6];
    const float* ro_b = (const float*)d_in[7];
    (void)in_sizes; (void)n_in; (void)out_size; (void)d_ws; (void)ws_size;
    float* out = (float*)d_out;

    proj_gemm<<<dim3((NB * NS) / 256), dim3(256), 0, stream>>>(x, ctx, Wf_w, Wf_b, Wh_w, Wh_b, out);
    agent_scan<<<dim3(NB), dim3(64), 0, stream>>>(Wf_w, Wh_w, ro_w, ro_b, out);
}